// Round 11
// baseline (59.877 us; speedup 1.0000x reference)
//
#include <hip/hip_runtime.h>

#define BB 4096
#define TT 80
#define VV 10000
#define EE 100
#define HH 64

typedef _Float16 f16x8 __attribute__((ext_vector_type(8)));
typedef _Float16 f16x4 __attribute__((ext_vector_type(4)));
typedef __attribute__((ext_vector_type(4))) float f4v;
typedef __attribute__((ext_vector_type(4))) unsigned u4v;

#define MFMA(w, s, c) __builtin_amdgcn_mfma_f32_16x16x32_f16((w), (s), (c), 0, 0, 0)

// Raw barrier: drains LDS ops (lgkm) but lets global loads stay in flight.
#define BAR() do { asm volatile("s_waitcnt lgkmcnt(0)" ::: "memory"); \
                   __builtin_amdgcn_s_barrier();                      \
                   asm volatile("" ::: "memory"); } while (0)

// tanh(x) = 1 - 2/(exp(2x)+1). +inf -> 1, -inf -> -1.
__device__ __forceinline__ float fast_tanh(float x) {
    float e = __builtin_amdgcn_exp2f(x * 2.8853900817779268f); // exp(2x)
    return 1.0f - 2.0f * __builtin_amdgcn_rcpf(e + 1.0f);
}

// k-PERMUTED weight A-fragment: slot (g,i) <- W[k][c] with
//   k = pi(kf,g,i) = 16*(i>>1) + 4*g + 2*kf + (i&1)
// pi is a bijection slot->k, so the MFMA contraction is unchanged; it is chosen
// so that the D-accumulator values a lane holds (cols 16t+4g+q, q=0..3) are
// EXACTLY its own next-step B-fragment slots: as0 elem i <- (t=i>>1, q=i&1),
// as1 elem i <- (t=i>>1, q=2+(i&1)).  D->B needs no cross-lane motion.
__device__ __forceinline__ void load_wfrag_pi(const float* __restrict__ W, int kf,
                                              int g, int c, f16x8& hi, f16x8& lo) {
    union { _Float16 h[8]; f16x8 v; } th, tl;
#pragma unroll
    for (int i = 0; i < 8; ++i) {
        int k = 16 * (i >> 1) + 4 * g + 2 * kf + (i & 1);
        float wv = W[k * HH + c];
        _Float16 hf = (_Float16)wv;          // RNE
        th.h[i] = hf;
        tl.h[i] = (_Float16)(wv - (float)hf);
    }
    hi = th.v;
    lo = tl.v;
}

// emb2h[v][j] = fp16( b0[j] + sum_e emb[v][e] * Wx0[e][j] )  (unchanged, proven)
__global__ __launch_bounds__(256) void emb2_kernel(const float* __restrict__ emb,
                                                   const float* __restrict__ Wx0,
                                                   const float* __restrict__ b0,
                                                   _Float16* __restrict__ emb2h) {
    const int tid = threadIdx.x;
    const int wid = tid >> 6;
    const int l = tid & 63;
    const int g = l >> 4;
    const int r16 = l & 15;
    const int c = 16 * wid + r16;
    const int jcol = 16 * wid + 4 * g;
    const int vr = blockIdx.x * 16 + r16;   // VV % 16 == 0

    f16x8 wa[4];   // Wx0^T hi frags (standard k-order; A and B consistent)
#pragma unroll
    for (int kf = 0; kf < 4; ++kf) {
        union { _Float16 h[8]; f16x8 v; } t;
#pragma unroll
        for (int i = 0; i < 8; ++i) {
            int e = 32 * kf + 8 * g + i;
            t.h[i] = (e < EE) ? (_Float16)Wx0[e * HH + c] : (_Float16)0.f;
        }
        wa[kf] = t.v;
    }
    const float* er = emb + (size_t)vr * EE;
    f4v acc = *(const f4v*)&b0[jcol];
#pragma unroll
    for (int kf = 0; kf < 4; ++kf) {
        union { _Float16 h[8]; f16x8 v; } tb;
#pragma unroll
        for (int i = 0; i < 8; ++i) {
            int e = 32 * kf + 8 * g + i;
            tb.h[i] = (e < EE) ? (_Float16)er[e] : (_Float16)0.f;
        }
        acc = MFMA(wa[kf], tb.v, acc);
    }
    f16x4 o;
#pragma unroll
    for (int q = 0; q < 4; ++q) o[q] = (_Float16)acc[q];
    *(f16x4*)&emb2h[(size_t)vr * HH + jcol] = o;
}

// Barrier-free-recurrence pipeline: 256 blocks x 4 waves (1/SIMD), 16 rows.
// w0: h0(p) = tanh(x(p) + Wh0^T h0(p-1))   — chain fully in-register (pi trick);
//     writes packed h0 frags to ring HR[p&7] for the P waves.
// w2/w3: P(p) = b1 + Wx1^T h0(p) (2 col-tiles each) -> f32 ring PR[p&7].
// w1: h1(p) = tanh(P(p) + Wh1^T h1(p-1))   — chain in-register, lags 8 steps.
// One barrier per 4-step GROUP (22 barriers total vs 81 per-phase before).
// Group schedule (wall group Wg): w0 does steps 4Wg..+3 (Wg<20); P does group
// Wg-1; h1 does group Wg-2. Ring depth 8 = 2 groups => no WAR hazards.
__global__ __launch_bounds__(256, 1) void rnn_pipe(
    const int* __restrict__ tokens, const _Float16* __restrict__ emb2,
    const float* __restrict__ Wh0, const float* __restrict__ Wx1,
    const float* __restrict__ Wh1, const float* __restrict__ b1,
    const float* __restrict__ Wout, const float* __restrict__ bout,
    float* __restrict__ out) {
    __shared__ __align__(16) unsigned HR[8][16 * 36];     // h0 frags: [n*36 + kf*16 + g*4]
    __shared__ __align__(16) float    PR[8][4 * 16 * 20]; // P: [(t*16+n)*20 + g*4]
    __shared__ int tokB[TT][16];                          // byte offsets (<<7)

    const int tid = threadIdx.x;
    const int wid = tid >> 6;        // 0=h0-chain, 1=h1-chain, 2/3=P
    const int l = tid & 63;
    const int g = l >> 4;
    const int r16 = l & 15;
    const int R = blockIdx.x * 16;

    for (int i = tid; i < 16 * TT; i += 256) {
        int r = i / TT, t = i - r * TT;
        tokB[t][r] = tokens[R * TT + i] << 7;
    }

    const f4v z4 = {0.f, 0.f, 0.f, 0.f};
    const char* ebase = (const char*)emb2;
    const int hrW = r16 * 36 + g * 4;   // HR dword base (kf0); kf1 at +16

    if (wid == 0) {
        // ---------------- h0 chain ----------------
        f16x8 wh[4][2], wl[4][2];
#pragma unroll
        for (int t = 0; t < 4; ++t) {
            int c = 16 * t + r16;
            load_wfrag_pi(Wh0, 0, g, c, wh[t][0], wl[t][0]);
            load_wfrag_pi(Wh0, 1, g, c, wh[t][1], wl[t][1]);
        }
        BAR();   // tokens staged
        f16x8 f0 = (f16x8)0, f1 = (f16x8)0;   // h0(p-1) B-frags (kf0, kf1)
        f16x4 xb[2][4][4];                     // x prefetch, double-buffered by group
#pragma unroll
        for (int s = 0; s < 4; ++s) {          // prologue: gather group 0
            int tb = tokB[s][r16];
#pragma unroll
            for (int t = 0; t < 4; ++t)
                xb[0][s][t] = *(const f16x4*)(ebase + tb + (16 * t + 4 * g) * 2);
        }
#pragma unroll 2
        for (int Wg = 0; Wg < 22; ++Wg) {
            if (Wg + 1 < 20) {                 // prefetch next group's x
#pragma unroll
                for (int s = 0; s < 4; ++s) {
                    int tb = tokB[4 * (Wg + 1) + s][r16];
#pragma unroll
                    for (int t = 0; t < 4; ++t)
                        xb[(Wg + 1) & 1][s][t] =
                            *(const f16x4*)(ebase + tb + (16 * t + 4 * g) * 2);
                }
            }
            if (Wg < 20) {
#pragma unroll
                for (int s = 0; s < 4; ++s) {
                    const int p = 4 * Wg + s;
                    f4v acc[4];
#pragma unroll
                    for (int t = 0; t < 4; ++t) {
                        f16x4 xr = xb[Wg & 1][s][t];
                        f4v A1 = {(float)xr[0], (float)xr[1],
                                  (float)xr[2], (float)xr[3]};
                        A1 = MFMA(wh[t][0], f0, A1);
                        A1 = MFMA(wh[t][1], f1, A1);
                        f4v A2 = MFMA(wl[t][0], f0, z4);
                        A2 = MFMA(wl[t][1], f1, A2);
                        acc[t] = A1 + A2;
                    }
                    union { _Float16 h[8]; f16x8 v; u4v u; } p0, p1;
#pragma unroll
                    for (int t = 0; t < 4; ++t) {
                        p0.h[2 * t]     = (_Float16)fast_tanh(acc[t][0]);
                        p0.h[2 * t + 1] = (_Float16)fast_tanh(acc[t][1]);
                        p1.h[2 * t]     = (_Float16)fast_tanh(acc[t][2]);
                        p1.h[2 * t + 1] = (_Float16)fast_tanh(acc[t][3]);
                    }
                    f0 = p0.v; f1 = p1.v;       // next-step B-frags: in-register!
                    const int sl = p & 7;
                    *(u4v*)&HR[sl][hrW]      = p0.u;
                    *(u4v*)&HR[sl][hrW + 16] = p1.u;
                }
            }
            BAR();
        }
    } else if (wid == 1) {
        // ---------------- h1 chain ----------------
        f16x8 wh[4][2], wl[4][2];
        f4v wov[4];
#pragma unroll
        for (int t = 0; t < 4; ++t) {
            int c = 16 * t + r16;
            load_wfrag_pi(Wh1, 0, g, c, wh[t][0], wl[t][0]);
            load_wfrag_pi(Wh1, 1, g, c, wh[t][1], wl[t][1]);
            wov[t] = *(const f4v*)&Wout[16 * t + 4 * g];
        }
        const float bo = bout[0];
        BAR();
        f16x8 f0 = (f16x8)0, f1 = (f16x8)0;   // h1(p-1) B-frags
        float vv[4][4] = {};                   // last-step tanh values (h1(79))
#pragma unroll 2
        for (int Wg = 0; Wg < 22; ++Wg) {
            if (Wg >= 2) {
                f4v pr[4][4];
#pragma unroll
                for (int s = 0; s < 4; ++s) {   // group-prefetch P (visible: Wg-1)
                    const int sl = (4 * (Wg - 2) + s) & 7;
#pragma unroll
                    for (int t = 0; t < 4; ++t)
                        pr[s][t] = *(const f4v*)&PR[sl][(t * 16 + r16) * 20 + g * 4];
                }
#pragma unroll
                for (int s = 0; s < 4; ++s) {
                    f4v acc[4];
#pragma unroll
                    for (int t = 0; t < 4; ++t) {
                        f4v A1 = pr[s][t];
                        A1 = MFMA(wh[t][0], f0, A1);
                        A1 = MFMA(wh[t][1], f1, A1);
                        f4v A2 = MFMA(wl[t][0], f0, z4);
                        A2 = MFMA(wl[t][1], f1, A2);
                        acc[t] = A1 + A2;
                    }
                    union { _Float16 h[8]; f16x8 v; } p0, p1;
#pragma unroll
                    for (int t = 0; t < 4; ++t) {
                        vv[t][0] = fast_tanh(acc[t][0]);
                        vv[t][1] = fast_tanh(acc[t][1]);
                        vv[t][2] = fast_tanh(acc[t][2]);
                        vv[t][3] = fast_tanh(acc[t][3]);
                        p0.h[2 * t]     = (_Float16)vv[t][0];
                        p0.h[2 * t + 1] = (_Float16)vv[t][1];
                        p1.h[2 * t]     = (_Float16)vv[t][2];
                        p1.h[2 * t + 1] = (_Float16)vv[t][3];
                    }
                    f0 = p0.v; f1 = p1.v;
                }
            }
            BAR();
        }
        // epilogue: out = sigmoid(h1(79) @ Wout + bout); lane holds 16 m-values
        float pp = 0.f;
#pragma unroll
        for (int t = 0; t < 4; ++t)
#pragma unroll
            for (int q = 0; q < 4; ++q)
                pp = fmaf(vv[t][q], wov[t][q], pp);
        pp += __shfl_xor(pp, 16, 64);
        pp += __shfl_xor(pp, 32, 64);
        if (l < 16) {
            float logit = pp + bo;
            out[R + l] = __builtin_amdgcn_rcpf(
                1.0f + __builtin_amdgcn_exp2f(-1.4426950408889634f * logit));
        }
    } else {
        // ---------------- P producers (wid 2: tiles 0,1; wid 3: tiles 2,3) ---
        const int t0 = 2 * (wid - 2);
        f16x8 wxh[2][2], wxl[2][2];
        f4v b1v[2];
#pragma unroll
        for (int tt = 0; tt < 2; ++tt) {
            int c = 16 * (t0 + tt) + r16;
            load_wfrag_pi(Wx1, 0, g, c, wxh[tt][0], wxl[tt][0]);
            load_wfrag_pi(Wx1, 1, g, c, wxh[tt][1], wxl[tt][1]);
            b1v[tt] = *(const f4v*)&b1[16 * (t0 + tt) + 4 * g];
        }
        BAR();
#pragma unroll 2
        for (int Wg = 0; Wg < 22; ++Wg) {
            if (Wg >= 1 && Wg <= 20) {
                f16x8 fr0[4], fr1[4];
#pragma unroll
                for (int s = 0; s < 4; ++s) {   // group-prefetch h0 frags (Wg-1)
                    const int sl = (4 * (Wg - 1) + s) & 7;
                    fr0[s] = *(const f16x8*)&HR[sl][hrW];
                    fr1[s] = *(const f16x8*)&HR[sl][hrW + 16];
                }
#pragma unroll
                for (int s = 0; s < 4; ++s) {
                    const int sl = (4 * (Wg - 1) + s) & 7;
#pragma unroll
                    for (int tt = 0; tt < 2; ++tt) {
                        f4v C1 = b1v[tt];
                        C1 = MFMA(wxh[tt][0], fr0[s], C1);
                        C1 = MFMA(wxh[tt][1], fr1[s], C1);
                        f4v C2 = MFMA(wxl[tt][0], fr0[s], z4);
                        C2 = MFMA(wxl[tt][1], fr1[s], C2);
                        f4v P = C1 + C2;
                        *(f4v*)&PR[sl][((t0 + tt) * 16 + r16) * 20 + g * 4] = P;
                    }
                }
            }
            BAR();
        }
    }
}

extern "C" void kernel_launch(void* const* d_in, const int* in_sizes, int n_in,
                              void* d_out, int out_size, void* d_ws, size_t ws_size,
                              hipStream_t stream) {
    const int*   tokens = (const int*)  d_in[0];
    const float* emb    = (const float*)d_in[1];
    const float* Wx0    = (const float*)d_in[2];
    const float* Wh0    = (const float*)d_in[3];
    const float* b0     = (const float*)d_in[4];
    const float* Wx1    = (const float*)d_in[5];
    const float* Wh1    = (const float*)d_in[6];
    const float* b1     = (const float*)d_in[7];
    const float* Wout   = (const float*)d_in[8];
    const float* bout   = (const float*)d_in[9];
    float* out  = (float*)d_out;
    _Float16* emb2h = (_Float16*)d_ws;   // VV*HH fp16 = 1.28 MB

    emb2_kernel<<<VV / 16, 256, 0, stream>>>(emb, Wx0, b0, emb2h);
    rnn_pipe<<<BB / 16, 256, 0, stream>>>(tokens, emb2h, Wh0, Wx1, Wh1, b1,
                                          Wout, bout, out);
}

// Round 12
// 54.021 us; speedup vs baseline: 1.1084x; 1.1084x over previous
//
#include <hip/hip_runtime.h>

#define BB 4096
#define TT 80
#define VV 10000
#define EE 100
#define HH 64
#define STR 68    // fp16 row stride: 136 B/row; bursts at bank minimum (R6-verified)
#define STRP 68   // f32 row stride for the P ring

typedef _Float16 f16x8 __attribute__((ext_vector_type(8)));
typedef _Float16 f16x4 __attribute__((ext_vector_type(4)));
typedef __attribute__((ext_vector_type(4))) float f4v;   // 4 fp32

// Transposed compute: D = A(W^T frag) * B(state frag) + C -> lane holds
// (batch row = l&15, 4 adjacent hidden cols = 4*(l>>4)+q)
#define MFMA(w, s, c) __builtin_amdgcn_mfma_f32_16x16x32_f16((w), (s), (c), 0, 0, 0)

// Raw barrier: drains LDS ops (lgkm) but lets global loads stay in flight.
#define BAR() do { asm volatile("s_waitcnt lgkmcnt(0)" ::: "memory"); \
                   __builtin_amdgcn_s_barrier();                      \
                   asm volatile("" ::: "memory"); } while (0)

// tanh(x) = 1 - 2/(exp(2x)+1). +inf -> 1, -inf -> -1.
__device__ __forceinline__ float fast_tanh(float x) {
    float e = __builtin_amdgcn_exp2f(x * 2.8853900817779268f); // exp(2x)
    return 1.0f - 2.0f * __builtin_amdgcn_rcpf(e + 1.0f);
}

// Weight fragment (hi/lo fp16) for W[k][c]: frag elem i <- W[32*kf + 8*g + i][c]
__device__ __forceinline__ void load_wfrag(const float* __restrict__ W, int kf, int g,
                                           int c, f16x8& hi, f16x8& lo) {
    union { _Float16 h[8]; f16x8 v; } th, tl;
#pragma unroll
    for (int i = 0; i < 8; ++i) {
        float wv = W[(32 * kf + 8 * g + i) * HH + c];
        _Float16 hf = (_Float16)wv;          // RNE
        th.h[i] = hf;
        tl.h[i] = (_Float16)(wv - (float)hf);
    }
    hi = th.v;
    lo = tl.v;
}

// emb2h[v][j] = fp16( b0[j] + sum_e emb[v][e] * Wx0[e][j] )  (unchanged, proven)
__global__ __launch_bounds__(256) void emb2_kernel(const float* __restrict__ emb,
                                                   const float* __restrict__ Wx0,
                                                   const float* __restrict__ b0,
                                                   _Float16* __restrict__ emb2h) {
    const int tid = threadIdx.x;
    const int wid = tid >> 6;
    const int l = tid & 63;
    const int g = l >> 4;
    const int r16 = l & 15;
    const int c = 16 * wid + r16;
    const int jcol = 16 * wid + 4 * g;
    const int vr = blockIdx.x * 16 + r16;   // VV % 16 == 0

    f16x8 wa[4];   // Wx0^T hi frags, K = 128 (zero-pad e >= 100)
#pragma unroll
    for (int kf = 0; kf < 4; ++kf) {
        union { _Float16 h[8]; f16x8 v; } t;
#pragma unroll
        for (int i = 0; i < 8; ++i) {
            int e = 32 * kf + 8 * g + i;
            t.h[i] = (e < EE) ? (_Float16)Wx0[e * HH + c] : (_Float16)0.f;
        }
        wa[kf] = t.v;
    }
    const float* er = emb + (size_t)vr * EE;
    f4v acc = *(const f4v*)&b0[jcol];
#pragma unroll
    for (int kf = 0; kf < 4; ++kf) {
        union { _Float16 h[8]; f16x8 v; } tb;
#pragma unroll
        for (int i = 0; i < 8; ++i) {
            int e = 32 * kf + 8 * g + i;
            tb.h[i] = (e < EE) ? (_Float16)er[e] : (_Float16)0.f;
        }
        acc = MFMA(wa[kf], tb.v, acc);
    }
    f16x4 o;
#pragma unroll
    for (int q = 0; q < 4; ++q) o[q] = (_Float16)acc[q];
    *(f16x4*)&emb2h[(size_t)vr * HH + jcol] = o;
}

// Rebalanced layer-split (R9 + P-export): 256 blocks x 512 thr (2 waves/SIMD).
// Waves 0-3 (L0, tile=w8):   h0(p) = tanh(x(p) + Wh0^T h0(p-1))      [chain: 4 MFMA]
//                            P(p-1) = b1 + Wx1^T h0(p-1)  -> f32 ring [off-chain]
// Waves 4-7 (L1, tile=w8-4): h1(p-2) = tanh(P(p-2) + Wh1^T h1(p-3))  [chain: 4 MFMA]
// Both roles' recurrence chains are 4-MFMA deep (R9's L1 was 8). P passes raw
// f32 (no precision loss; read as MFMA C-init). One BAR per phase; 82 phases.
__global__ __launch_bounds__(512, 1) void rnn_pipe(
    const int* __restrict__ tokens, const _Float16* __restrict__ emb2,
    const float* __restrict__ Wh0, const float* __restrict__ Wx1,
    const float* __restrict__ Wh1, const float* __restrict__ b1,
    const float* __restrict__ Wout, const float* __restrict__ bout,
    float* __restrict__ out) {
    __shared__ __align__(16) _Float16 H0[2][16][STR];
    __shared__ __align__(16) _Float16 H1[2][16][STR];
    __shared__ __align__(16) float PP[2][16][STRP];
    __shared__ __align__(16) int tokT[TT][16];   // [t][row], byte-scaled (<<7)
    __shared__ float Pred[4][16];

    const int tid = threadIdx.x;
    const int w8 = tid >> 6;         // 0..7
    const int l = tid & 63;
    const int g = l >> 4;
    const int r16 = l & 15;          // my batch row
    const bool isL0 = (w8 < 4);
    const int tile = isL0 ? w8 : (w8 - 4);
    const int c = 16 * tile + r16;   // weight column for A-fragment loads
    const int jcol = 16 * tile + 4 * g;  // my 4 output cols
    const int R = blockIdx.x * 16;   // base batch row

    for (int i = tid; i < 16 * TT; i += 512) {
        int r = i / TT, t = i - r * TT;              // coalesced global read
        tokT[t][r] = tokens[R * TT + i] << 7;        // row stride 64 fp16 = 128 B
    }

    // Role weights: L0 -> Wh0 (chain) + Wx1 (P export); L1 -> Wh1 (chain).
    f16x8 wAh[2], wAl[2], wBh[2], wBl[2];
    if (isL0) {
        load_wfrag(Wh0, 0, g, c, wAh[0], wAl[0]);
        load_wfrag(Wh0, 1, g, c, wAh[1], wAl[1]);
        load_wfrag(Wx1, 0, g, c, wBh[0], wBl[0]);
        load_wfrag(Wx1, 1, g, c, wBh[1], wBl[1]);
    } else {
        load_wfrag(Wh1, 0, g, c, wAh[0], wAl[0]);
        load_wfrag(Wh1, 1, g, c, wAh[1], wAl[1]);
        wBh[0] = wBh[1] = wBl[0] = wBl[1] = (f16x8)0;
    }
    const f4v b1v = *(const f4v*)&b1[jcol];
    const f4v wov = *(const f4v*)&Wout[jcol];
    const f4v z4 = {0.f, 0.f, 0.f, 0.f};
    const char* ebase = (const char*)emb2 + (size_t)jcol * 2;

    BAR();   // tokens staged

    f16x8 a0[2] = {(f16x8)0, (f16x8)0};   // L0: h0(p-1) frags; L1: h1(p-3) frags
    f4v Pin = z4;                          // L1: P(p-2), read one phase ahead
    f16x4 xc = (f16x4)0, xn = (f16x4)0;   // raw fp16 gathers (L0 only)

    // ---- phase 0: L0 writes h0(0) = tanh(x(0)) ----
    if (isL0) {
        xc = *(const f16x4*)(ebase + tokT[0][r16]);
        xn = *(const f16x4*)(ebase + tokT[1][r16]);
        f16x4 ph;
#pragma unroll
        for (int q = 0; q < 4; ++q) ph[q] = (_Float16)fast_tanh((float)xc[q]);
        *(f16x4*)&H0[0][r16][jcol] = ph;
        xc = xn;
    }
    BAR();
    if (isL0) {
        a0[0] = *(const f16x8*)&H0[0][r16][8 * g];
        a0[1] = *(const f16x8*)&H0[0][r16][32 + 8 * g];
    }

    // ---- main loop p = 1..80 ----
#pragma unroll 2
    for (int p = 1; p <= 80; ++p) {
        const int par = p & 1;
        if (isL0) {
            // h0(p), p <= 79 — the recurrence chain (4 MFMA + 4 tanh)
            if (p <= TT - 1) {
                if (p <= TT - 2)   // prefetch x(p+1); floats across BAR
                    xn = *(const f16x4*)(ebase + tokT[p + 1][r16]);
                f4v A1 = {(float)xc[0], (float)xc[1], (float)xc[2], (float)xc[3]};
                A1 = MFMA(wAh[0], a0[0], A1);
                A1 = MFMA(wAh[1], a0[1], A1);
                f4v A2 = MFMA(wAl[0], a0[0], z4);
                A2 = MFMA(wAl[1], a0[1], A2);
                f4v acc0 = A1 + A2;
                f16x4 p0;
#pragma unroll
                for (int q = 0; q < 4; ++q) p0[q] = (_Float16)fast_tanh(acc0[q]);
                *(f16x4*)&H0[par][r16][jcol] = p0;
                xc = xn;
            }
            // P(p-1) = b1 + Wx1^T h0(p-1) — off-chain export, raw f32
            f4v C1 = b1v;
            C1 = MFMA(wBh[0], a0[0], C1);
            C1 = MFMA(wBh[1], a0[1], C1);
            f4v C2 = MFMA(wBl[0], a0[0], z4);
            C2 = MFMA(wBl[1], a0[1], C2);
            *(f4v*)&PP[par][r16][jcol] = C1 + C2;
        } else {
            // h1(p-2) = tanh(P(p-2) + Wh1^T h1(p-3)) — 4 MFMA, P as C-init
            if (p >= 2) {
                f4v C1 = Pin;
                C1 = MFMA(wAh[0], a0[0], C1);
                C1 = MFMA(wAh[1], a0[1], C1);
                f4v C2 = MFMA(wAl[0], a0[0], z4);
                C2 = MFMA(wAl[1], a0[1], C2);
                f4v acc1 = C1 + C2;
                f16x4 p1;
#pragma unroll
                for (int q = 0; q < 4; ++q) p1[q] = (_Float16)fast_tanh(acc1[q]);
                *(f16x4*)&H1[par][r16][jcol] = p1;
            }
        }
        BAR();
        if (isL0) {
            if (p <= TT - 1) {       // h0(p) frags for next phase
                a0[0] = *(const f16x8*)&H0[par][r16][8 * g];
                a0[1] = *(const f16x8*)&H0[par][r16][32 + 8 * g];
            }
        } else {
            if (p >= 2) {            // h1(p-2) frags for next phase
                a0[0] = *(const f16x8*)&H1[par][r16][8 * g];
                a0[1] = *(const f16x8*)&H1[par][r16][32 + 8 * g];
            }
            // P(p-1), written by L0 this phase; used next phase as C-init
            Pin = *(const f4v*)&PP[par][r16][jcol];
        }
    }

    // ---- phase 81 (par 1): L1 computes h1(79) in-register + epilogue ----
    if (!isL0) {
        f4v C1 = Pin;                         // P(79)
        C1 = MFMA(wAh[0], a0[0], C1);         // a0 = h1(78) frags
        C1 = MFMA(wAh[1], a0[1], C1);
        f4v C2 = MFMA(wAl[0], a0[0], z4);
        C2 = MFMA(wAl[1], a0[1], C2);
        f4v acc1 = C1 + C2;
        // out = sigmoid(h1(79) @ Wout + bout): lane holds 4 cols of row r16
        float pp = fast_tanh(acc1[0]) * wov[0];
        pp = fmaf(fast_tanh(acc1[1]), wov[1], pp);
        pp = fmaf(fast_tanh(acc1[2]), wov[2], pp);
        pp = fmaf(fast_tanh(acc1[3]), wov[3], pp);
        pp += __shfl_xor(pp, 16, 64);   // sum over g-groups
        pp += __shfl_xor(pp, 32, 64);
        if (l < 16) Pred[tile][l] = pp;
    }
    BAR();
    if (tid < 16) {
        float logit = Pred[0][tid] + Pred[1][tid] + Pred[2][tid] +
                      Pred[3][tid] + bout[0];
        out[R + tid] = __builtin_amdgcn_rcpf(
            1.0f + __builtin_amdgcn_exp2f(-1.4426950408889634f * logit));
    }
}

extern "C" void kernel_launch(void* const* d_in, const int* in_sizes, int n_in,
                              void* d_out, int out_size, void* d_ws, size_t ws_size,
                              hipStream_t stream) {
    const int*   tokens = (const int*)  d_in[0];
    const float* emb    = (const float*)d_in[1];
    const float* Wx0    = (const float*)d_in[2];
    const float* Wh0    = (const float*)d_in[3];
    const float* b0     = (const float*)d_in[4];
    const float* Wx1    = (const float*)d_in[5];
    const float* Wh1    = (const float*)d_in[6];
    const float* b1     = (const float*)d_in[7];
    const float* Wout   = (const float*)d_in[8];
    const float* bout   = (const float*)d_in[9];
    float* out  = (float*)d_out;
    _Float16* emb2h = (_Float16*)d_ws;   // VV*HH fp16 = 1.28 MB

    emb2_kernel<<<VV / 16, 256, 0, stream>>>(emb, Wx0, b0, emb2h);
    rnn_pipe<<<BB / 16, 512, 0, stream>>>(tokens, emb2h, Wh0, Wx1, Wh1, b1,
                                          Wout, bout, out);
}

// Round 13
// 38.126 us; speedup vs baseline: 1.5705x; 1.4169x over previous
//
#include <hip/hip_runtime.h>

#define BB 4096
#define TT 80
#define VV 10000
#define EE 100
#define HH 64
#define STR 68   // fp16 row stride: 136 B/row; bursts at bank minimum (R6-verified)

typedef _Float16 f16x8 __attribute__((ext_vector_type(8)));
typedef _Float16 f16x4 __attribute__((ext_vector_type(4)));
typedef __attribute__((ext_vector_type(4))) float f4v;   // 4 fp32

// Transposed compute: D = A(W^T frag) * B(state frag) + C -> lane holds
// (batch row = l&15, 4 adjacent hidden cols = 4*(l>>4)+q)
#define MFMA(w, s, c) __builtin_amdgcn_mfma_f32_16x16x32_f16((w), (s), (c), 0, 0, 0)

// Raw barrier: drains LDS ops (lgkm) but lets global loads stay in flight.
#define BAR() do { asm volatile("s_waitcnt lgkmcnt(0)" ::: "memory"); \
                   __builtin_amdgcn_s_barrier();                      \
                   asm volatile("" ::: "memory"); } while (0)

// tanh(x) = 1 - 2/(exp(2x)+1). +inf -> 1, -inf -> -1.
__device__ __forceinline__ float fast_tanh(float x) {
    float e = __builtin_amdgcn_exp2f(x * 2.8853900817779268f); // exp(2x)
    return 1.0f - 2.0f * __builtin_amdgcn_rcpf(e + 1.0f);
}

// hi-only fp16 weight A-fragment for W[k][c]: frag elem i <- W[32*kf+8*g+i][c].
// RNE error ~6e-5/elem -> pre-activation noise ~2.4e-4, same scale as the
// fp16-state noise already in the pipeline (passing since R5; emb2 hi-only
// since R8).
__device__ __forceinline__ f16x8 load_wfrag_hi(const float* __restrict__ W, int kf,
                                               int g, int c) {
    union { _Float16 h[8]; f16x8 v; } th;
#pragma unroll
    for (int i = 0; i < 8; ++i)
        th.h[i] = (_Float16)W[(32 * kf + 8 * g + i) * HH + c];
    return th.v;
}

// emb2h[v][j] = fp16( b0[j] + sum_e emb[v][e] * Wx0[e][j] )  (unchanged, proven)
__global__ __launch_bounds__(256) void emb2_kernel(const float* __restrict__ emb,
                                                   const float* __restrict__ Wx0,
                                                   const float* __restrict__ b0,
                                                   _Float16* __restrict__ emb2h) {
    const int tid = threadIdx.x;
    const int wid = tid >> 6;
    const int l = tid & 63;
    const int g = l >> 4;
    const int r16 = l & 15;
    const int c = 16 * wid + r16;
    const int jcol = 16 * wid + 4 * g;
    const int vr = blockIdx.x * 16 + r16;   // VV % 16 == 0

    f16x8 wa[4];   // Wx0^T hi frags, K = 128 (zero-pad e >= 100)
#pragma unroll
    for (int kf = 0; kf < 4; ++kf) {
        union { _Float16 h[8]; f16x8 v; } t;
#pragma unroll
        for (int i = 0; i < 8; ++i) {
            int e = 32 * kf + 8 * g + i;
            t.h[i] = (e < EE) ? (_Float16)Wx0[e * HH + c] : (_Float16)0.f;
        }
        wa[kf] = t.v;
    }
    const float* er = emb + (size_t)vr * EE;
    f4v acc = *(const f4v*)&b0[jcol];
#pragma unroll
    for (int kf = 0; kf < 4; ++kf) {
        union { _Float16 h[8]; f16x8 v; } tb;
#pragma unroll
        for (int i = 0; i < 8; ++i) {
            int e = 32 * kf + 8 * g + i;
            tb.h[i] = (e < EE) ? (_Float16)er[e] : (_Float16)0.f;
        }
        acc = MFMA(wa[kf], tb.v, acc);
    }
    f16x4 o;
#pragma unroll
    for (int q = 0; q < 4; ++q) o[q] = (_Float16)acc[q];
    *(f16x4*)&emb2h[(size_t)vr * HH + jcol] = o;
}

// R9 structure, hi-only weights: 256 blocks x 512 thr (8 waves = 2/SIMD),
// 16 rows/block. Waves 0-3 (L0): h0(p) = tanh(x(p) + Wh0^T h0(p-1)) [2 MFMA].
// Waves 4-7 (L1): h1(p-1) = tanh(b1 + Wx1^T h0(p-1) + Wh1^T h1(p-2)) [4 MFMA].
// fp16 state in double-buffered LDS; one raw barrier per phase; 81 phases.
__global__ __launch_bounds__(512, 1) void rnn_pipe(
    const int* __restrict__ tokens, const _Float16* __restrict__ emb2,
    const float* __restrict__ Wh0, const float* __restrict__ Wx1,
    const float* __restrict__ Wh1, const float* __restrict__ b1,
    const float* __restrict__ Wout, const float* __restrict__ bout,
    float* __restrict__ out) {
    __shared__ __align__(16) _Float16 H0[2][16][STR];
    __shared__ __align__(16) _Float16 H1[2][16][STR];
    __shared__ __align__(16) int tokT[TT][16];   // [t][row], byte-scaled (<<7)
    __shared__ float Pred[4][16];

    const int tid = threadIdx.x;
    const int w8 = tid >> 6;         // 0..7
    const int l = tid & 63;
    const int g = l >> 4;
    const int r16 = l & 15;          // my batch row
    const bool isL0 = (w8 < 4);
    const int tile = isL0 ? w8 : (w8 - 4);
    const int c = 16 * tile + r16;   // weight column for A-fragment loads
    const int jcol = 16 * tile + 4 * g;  // my 4 output cols
    const int R = blockIdx.x * 16;   // base batch row

    for (int i = tid; i < 16 * TT; i += 512) {
        int r = i / TT, t = i - r * TT;              // coalesced global read
        tokT[t][r] = tokens[R * TT + i] << 7;        // row stride 64 fp16 = 128 B
    }

    // Role weights (hi-only): L0 -> wA = Wh0; L1 -> wA = Wx1, wB = Wh1.
    f16x8 wA[2], wB[2];
    if (isL0) {
        wA[0] = load_wfrag_hi(Wh0, 0, g, c);
        wA[1] = load_wfrag_hi(Wh0, 1, g, c);
        wB[0] = wB[1] = (f16x8)0;
    } else {
        wA[0] = load_wfrag_hi(Wx1, 0, g, c);
        wA[1] = load_wfrag_hi(Wx1, 1, g, c);
        wB[0] = load_wfrag_hi(Wh1, 0, g, c);
        wB[1] = load_wfrag_hi(Wh1, 1, g, c);
    }
    const f4v b1v = *(const f4v*)&b1[jcol];
    const f4v wov = *(const f4v*)&Wout[jcol];
    const f4v z4 = {0.f, 0.f, 0.f, 0.f};
    const char* ebase = (const char*)emb2 + (size_t)jcol * 2;

    BAR();   // tokens staged

    f16x8 a0[2] = {(f16x8)0, (f16x8)0};   // h0(p-1) fragments (kf=0,1)
    f16x8 a1[2] = {(f16x8)0, (f16x8)0};   // h1(p-2) fragments (L1 only)

    f16x4 xc = (f16x4)0, xn = (f16x4)0;   // raw fp16 gathers (L0 only)
    if (isL0) {
        xc = *(const f16x4*)(ebase + tokT[0][r16]);
        xn = *(const f16x4*)(ebase + tokT[1][r16]);
        // ---- phase 0: h0(0) = tanh(x0) ----
        f16x4 ph;
#pragma unroll
        for (int q = 0; q < 4; ++q) ph[q] = (_Float16)fast_tanh((float)xc[q]);
        *(f16x4*)&H0[0][r16][jcol] = ph;           // one b64 write
        xc = xn;
    }
    BAR();
    a0[0] = *(const f16x8*)&H0[0][r16][8 * g];
    a0[1] = *(const f16x8*)&H0[0][r16][32 + 8 * g];
    // a1 stays zero (h1(-1) = 0); H1[0] not yet written -> do not read it.

    // ---- main loop p = 1..TT-1 (par = p&1) ----
#pragma unroll 2
    for (int p = 1; p <= TT - 1; ++p) {
        const int par = p & 1;
        if (isL0) {
            // prefetch x(p+1) (clamped; x(TT-1) redundant re-gather at p=79)
            int pn = (p + 1 <= TT - 1) ? p + 1 : TT - 1;
            xn = *(const f16x4*)(ebase + tokT[pn][r16]);
            // h0(p): single chain of 2
            f4v A1 = {(float)xc[0], (float)xc[1], (float)xc[2], (float)xc[3]};
            A1 = MFMA(wA[0], a0[0], A1);
            A1 = MFMA(wA[1], a0[1], A1);
            f16x4 p0;
#pragma unroll
            for (int q = 0; q < 4; ++q) p0[q] = (_Float16)fast_tanh(A1[q]);
            *(f16x4*)&H0[par][r16][jcol] = p0;
            xc = xn;
        } else {
            // h1(p-1): 2 chains of 2
            f4v C1 = b1v;
            C1 = MFMA(wA[0], a0[0], C1);
            C1 = MFMA(wA[1], a0[1], C1);
            f4v C3 = MFMA(wB[0], a1[0], z4);
            C3 = MFMA(wB[1], a1[1], C3);
            f4v acc1 = C1 + C3;
            f16x4 p1;
#pragma unroll
            for (int q = 0; q < 4; ++q) p1[q] = (_Float16)fast_tanh(acc1[q]);
            *(f16x4*)&H1[par][r16][jcol] = p1;
        }
        BAR();
        a0[0] = *(const f16x8*)&H0[par][r16][8 * g];
        a0[1] = *(const f16x8*)&H0[par][r16][32 + 8 * g];
        if (!isL0) {
            a1[0] = *(const f16x8*)&H1[par][r16][8 * g];
            a1[1] = *(const f16x8*)&H1[par][r16][32 + 8 * g];
        }
    }

    // ---- p = TT = 80: L1 only -> h1(79) stays in registers; epilogue ----
    if (!isL0) {
        f4v C1 = b1v;
        C1 = MFMA(wA[0], a0[0], C1);
        C1 = MFMA(wA[1], a0[1], C1);
        f4v C3 = MFMA(wB[0], a1[0], z4);
        C3 = MFMA(wB[1], a1[1], C3);
        f4v acc1 = C1 + C3;
        // out = sigmoid(h1(79) @ Wout + bout): lane holds 4 cols of row r16
        float pp = fast_tanh(acc1[0]) * wov[0];
        pp = fmaf(fast_tanh(acc1[1]), wov[1], pp);
        pp = fmaf(fast_tanh(acc1[2]), wov[2], pp);
        pp = fmaf(fast_tanh(acc1[3]), wov[3], pp);
        pp += __shfl_xor(pp, 16, 64);   // sum over g-groups
        pp += __shfl_xor(pp, 32, 64);
        if (l < 16) Pred[tile][l] = pp;
    }
    BAR();
    if (tid < 16) {
        float logit = Pred[0][tid] + Pred[1][tid] + Pred[2][tid] +
                      Pred[3][tid] + bout[0];
        out[R + tid] = __builtin_amdgcn_rcpf(
            1.0f + __builtin_amdgcn_exp2f(-1.4426950408889634f * logit));
    }
}

extern "C" void kernel_launch(void* const* d_in, const int* in_sizes, int n_in,
                              void* d_out, int out_size, void* d_ws, size_t ws_size,
                              hipStream_t stream) {
    const int*   tokens = (const int*)  d_in[0];
    const float* emb    = (const float*)d_in[1];
    const float* Wx0    = (const float*)d_in[2];
    const float* Wh0    = (const float*)d_in[3];
    const float* b0     = (const float*)d_in[4];
    const float* Wx1    = (const float*)d_in[5];
    const float* Wh1    = (const float*)d_in[6];
    const float* b1     = (const float*)d_in[7];
    const float* Wout   = (const float*)d_in[8];
    const float* bout   = (const float*)d_in[9];
    float* out  = (float*)d_out;
    _Float16* emb2h = (_Float16*)d_ws;   // VV*HH fp16 = 1.28 MB

    emb2_kernel<<<VV / 16, 256, 0, stream>>>(emb, Wx0, b0, emb2h);
    rnn_pipe<<<BB / 16, 512, 0, stream>>>(tokens, emb2h, Wh0, Wx1, Wh1, b1,
                                          Wout, bout, out);
}